// Round 8
// baseline (303.612 us; speedup 1.0000x reference)
//
#include <hip/hip_runtime.h>

// H2GCNConv: out[:, 0:128]   = segment_sum(w1 * x[col1], row1)
//            out[:, 128:256] = segment_sum(w2 * x[col2], row2)
// N = 50000, d = 128, out stride = 256 floats.
//
// Round 8: spmm split into 4 feature-quarters (32 cols). Per-quarter gather
// footprint 3.2 MB fits one XCD's 4 MB L2 (r7 counters: 35% L2-miss at
// 12.8 MB footprint, gather-latency-bound at 6.8 TB/s request rate).
// Quarter-major wave order keeps phases L2-resident. 8 lanes/edge x uint2 =
// one 64 B line per edge-quarter. Build reverted to r6 (128-row buckets,
// LDS-staged bucket_sort — r7's coarser streaming variant was -13 us).
// cvt fused into the hist launch.

#define N_NODES 50000
#define D 128
#define OUT_STRIDE 256

#define BUCKET_SHIFT 7                      // 128 rows / bucket (r6-proven)
#define BROWS (1 << BUCKET_SHIFT)
#define NBUCK ((N_NODES + BROWS - 1) >> BUCKET_SHIFT)   // 391
#define CHUNK 7168                          // edges per bin_scatter WG
#define CAP   5120                          // max records per bucket in LDS
#define HIST_BLOCKS 512

typedef float vf4 __attribute__((ext_vector_type(4)));

static inline size_t align256(size_t x) { return (x + 255) & ~(size_t)255; }

__device__ __forceinline__ unsigned f32_to_bf16_bits(float f) {
    unsigned u = __float_as_uint(f);
    return (u + 0x7fffu + ((u >> 16) & 1u)) >> 16;   // RNE
}

// ------- 1. prep: blocks [0,512) coarse hist; rest pack x -> quarter-major --

__global__ void __launch_bounds__(256) prep_kernel(
        const int* __restrict__ ei1, int E1,
        const int* __restrict__ ei2, int E2,
        int* __restrict__ bcnt,              // [2*NBUCK], pre-zeroed
        const float* __restrict__ x,
        uint2* __restrict__ xbq, int n4) {   // [4][N][8] uint2
    if (blockIdx.x < HIST_BLOCKS) {
        __shared__ int h[2 * NBUCK];
        for (int i = threadIdx.x; i < 2 * NBUCK; i += 256) h[i] = 0;
        __syncthreads();
        int q1 = E1 >> 2, q2 = E2 >> 2;
        long long total = q1 + q2;
        for (long long i = (long long)blockIdx.x * 256 + threadIdx.x; i < total;
             i += (long long)HIST_BLOCKS * 256) {
            if (i < q1) {
                int4 r = ((const int4*)ei1)[i];
                atomicAdd(&h[r.x >> BUCKET_SHIFT], 1);
                atomicAdd(&h[r.y >> BUCKET_SHIFT], 1);
                atomicAdd(&h[r.z >> BUCKET_SHIFT], 1);
                atomicAdd(&h[r.w >> BUCKET_SHIFT], 1);
            } else {
                int4 r = ((const int4*)ei2)[i - q1];
                atomicAdd(&h[NBUCK + (r.x >> BUCKET_SHIFT)], 1);
                atomicAdd(&h[NBUCK + (r.y >> BUCKET_SHIFT)], 1);
                atomicAdd(&h[NBUCK + (r.z >> BUCKET_SHIFT)], 1);
                atomicAdd(&h[NBUCK + (r.w >> BUCKET_SHIFT)], 1);
            }
        }
        if (blockIdx.x == 0) {   // tails if E not divisible by 4
            int t1 = E1 & 3, t2 = E2 & 3;
            int t = threadIdx.x;
            if (t < t1) atomicAdd(&h[ei1[(q1 << 2) + t] >> BUCKET_SHIFT], 1);
            else if (t - t1 < t2)
                atomicAdd(&h[NBUCK + (ei2[(q2 << 2) + (t - t1)] >> BUCKET_SHIFT)], 1);
        }
        __syncthreads();
        for (int i = threadIdx.x; i < 2 * NBUCK; i += 256)
            if (h[i]) atomicAdd(&bcnt[i], h[i]);
    } else {
        // pack x: float4 i -> uint2 at quarter-major position
        int i = (blockIdx.x - HIST_BLOCKS) * 256 + threadIdx.x;
        if (i >= n4) return;
        float4 v = ((const float4*)x)[i];
        int node = i >> 5;          // 32 float4 per node
        int c4   = i & 31;          // float4 index within node
        int q    = c4 >> 3;         // quarter (8 float4 per quarter)
        int k    = c4 & 7;          // uint2 slot within quarter
        unsigned a = f32_to_bf16_bits(v.x);
        unsigned b = f32_to_bf16_bits(v.y);
        unsigned c = f32_to_bf16_bits(v.z);
        unsigned d = f32_to_bf16_bits(v.w);
        xbq[((size_t)q * N_NODES + node) * 8 + k] =
            make_uint2(a | (b << 16), c | (d << 16));
    }
}

// ---------------- 2. scan bucket counts -> bases (1 workgroup) -------------

__global__ void __launch_bounds__(256) bucket_scan(
        const int* __restrict__ bcnt, int* __restrict__ bsBase,
        int* __restrict__ bsFill) {
    __shared__ int wsum[4];
    int t = threadIdx.x, lane = t & 63, wid = t >> 6;
    for (int g = 0; g < 2; ++g) {
        const int* c = bcnt + g * NBUCK;
        int i0 = 2 * t, i1 = 2 * t + 1;
        int v0 = (i0 < NBUCK) ? c[i0] : 0;
        int v1 = (i1 < NBUCK) ? c[i1] : 0;
        int p = v0 + v1, s = p;
        #pragma unroll
        for (int d = 1; d < 64; d <<= 1) { int u = __shfl_up(s, d, 64); if (lane >= d) s += u; }
        if (lane == 63) wsum[wid] = s;
        __syncthreads();
        int add = 0;
        #pragma unroll
        for (int k = 0; k < 4; ++k) if (k < wid) add += wsum[k];
        s += add;                      // inclusive over pairs
        int excl = s - p;
        if (i0 < NBUCK) { bsBase[g * NBUCK + i0] = excl;      bsFill[g * NBUCK + i0] = excl; }
        if (i1 < NBUCK) { bsBase[g * NBUCK + i1] = excl + v0; bsFill[g * NBUCK + i1] = excl + v0; }
        __syncthreads();               // wsum reuse
    }
}

// ---------------- 3. binned scatter: edges -> bucket-grouped records -------

__global__ void __launch_bounds__(256) bin_scatter(
        const int* __restrict__ ei1, const float* __restrict__ w1, int E1, int nch1,
        const int* __restrict__ ei2, const float* __restrict__ w2, int E2,
        int* __restrict__ bsFill, uint2* __restrict__ inter) {
    int g, chunk;
    if ((int)blockIdx.x < nch1) { g = 0; chunk = blockIdx.x; }
    else                        { g = 1; chunk = blockIdx.x - nch1; }
    const int*   ei = g ? ei2 : ei1;
    const float* w  = g ? w2  : w1;
    int E           = g ? E2  : E1;
    uint2* out      = inter + (g ? E1 : 0);
    int*   fill     = bsFill + g * NBUCK;
    int e0  = chunk * CHUNK;
    int cnt = min(CHUNK, E - e0);

    __shared__ uint2 stage[CHUNK];              // 56 KB
    __shared__ int cntb[NBUCK], cur[NBUCK], gbase[NBUCK];
    __shared__ int wsum[4];
    int t = threadIdx.x, lane = t & 63, wid = t >> 6;
    for (int b = t; b < NBUCK; b += 256) cntb[b] = 0;
    __syncthreads();
    // pass 1: count bins
    for (int i = t; i < cnt; i += 256)
        atomicAdd(&cntb[ei[e0 + i] >> BUCKET_SHIFT], 1);
    __syncthreads();
    // exclusive scan over 391 bins (2 elems/thread)
    {
        int i0 = 2 * t, i1 = 2 * t + 1;
        int v0 = (i0 < NBUCK) ? cntb[i0] : 0;
        int v1 = (i1 < NBUCK) ? cntb[i1] : 0;
        int p = v0 + v1, s = p;
        #pragma unroll
        for (int d = 1; d < 64; d <<= 1) { int u = __shfl_up(s, d, 64); if (lane >= d) s += u; }
        if (lane == 63) wsum[wid] = s;
        __syncthreads();
        int add = 0;
        #pragma unroll
        for (int k = 0; k < 4; ++k) if (k < wid) add += wsum[k];
        s += add;
        int excl = s - p;
        if (i0 < NBUCK) cur[i0] = excl;
        if (i1 < NBUCK) cur[i1] = excl + v0;
    }
    __syncthreads();
    // reserve global space per bin
    for (int b = t; b < NBUCK; b += 256) {
        int c = cntb[b];
        gbase[b] = c ? atomicAdd(&fill[b], c) : 0;
    }
    __syncthreads();
    // pass 2: rank + stage
    for (int i = t; i < cnt; i += 256) {
        int row = ei[e0 + i];
        int col = ei[E + e0 + i];
        unsigned rec = (unsigned)col | (f32_to_bf16_bits(w[e0 + i]) << 16);
        int b = row >> BUCKET_SHIFT;
        int pos = atomicAdd(&cur[b], 1);
        stage[pos] = make_uint2((unsigned)(row & (BROWS - 1)), rec);
    }
    __syncthreads();
    // flush each bin as a contiguous burst (wave per bin, round-robin)
    for (int b = wid; b < NBUCK; b += 4) {
        int c = cntb[b];
        if (!c) continue;
        int s0 = cur[b] - c;         // cur[b] is now end-of-bin in stage
        int gb = gbase[b];
        for (int i = lane; i < c; i += 64)
            out[gb + i] = stage[s0 + i];
    }
}

// ---------------- 4. per-bucket counting sort (LDS-staged, r6) -------------

__global__ void __launch_bounds__(256) bucket_sort(
        const int* __restrict__ bsBase, const int* __restrict__ bsFill,
        const uint2* __restrict__ inter, unsigned* __restrict__ colw,
        int* __restrict__ off1, int* __restrict__ off2, int E1) {
    int b = blockIdx.x, g = blockIdx.y;
    int base = bsBase[g * NBUCK + b];
    int cnt  = bsFill[g * NBUCK + b] - base;
    const uint2* src = inter + (g ? E1 : 0) + base;
    unsigned*    dst = colw  + (g ? E1 : 0) + base;
    int*         off = g ? off2 : off1;

    __shared__ unsigned char rl[CAP];   // 5 KB
    __shared__ unsigned recs[CAP];      // 20 KB
    __shared__ unsigned outb[CAP];      // 20 KB
    __shared__ int crow[BROWS], cur[BROWS];
    __shared__ int wsum[4];
    int t = threadIdx.x, lane = t & 63, wid = t >> 6;
    if (t < BROWS) crow[t] = 0;
    __syncthreads();
    bool fits = (cnt <= CAP);
    // load (if fits) + count rows
    for (int i = t; i < cnt; i += 256) {
        uint2 v = src[i];
        if (fits) { rl[i] = (unsigned char)v.x; recs[i] = v.y; }
        atomicAdd(&crow[v.x], 1);
    }
    __syncthreads();
    // scan 128 row counts; write off ends
    int v = (t < BROWS) ? crow[t] : 0;
    int s = v;
    #pragma unroll
    for (int d = 1; d < 64; d <<= 1) { int u = __shfl_up(s, d, 64); if (lane >= d) s += u; }
    if (lane == 63) wsum[wid] = s;
    __syncthreads();
    int add = 0;
    #pragma unroll
    for (int k = 0; k < 4; ++k) if (k < wid) add += wsum[k];
    s += add;                           // inclusive
    if (t < BROWS) {
        cur[t] = s - v;                 // exclusive start within bucket
        int grow = (b << BUCKET_SHIFT) + t;
        if (grow < N_NODES) off[grow] = base + s;   // end of row's segment
    }
    __syncthreads();
    // scatter by row
    if (fits) {
        for (int i = t; i < cnt; i += 256) {
            int pos = atomicAdd(&cur[rl[i]], 1);
            outb[pos] = recs[i];
        }
        __syncthreads();
        for (int i = t; i < cnt; i += 256) dst[i] = outb[i];   // coalesced
    } else {
        for (int i = t; i < cnt; i += 256) {
            uint2 vv = src[i];
            int pos = atomicAdd(&cur[vv.x], 1);
            dst[pos] = vv.y;
        }
    }
}

// ---------------- 5. SpMM: quarter-split, 8 lanes/edge, uint2 gathers ------
// Wave = one (quarter, graph, row) segment; 8 edges in flight across 8-lane
// groups; each edge-quarter gather is one 64 B line from a 3.2 MB array.

__global__ void __launch_bounds__(256) spmm_bf16(
        const uint2* __restrict__ xbq,  // [4][N][8] uint2
        const int* __restrict__ off1, const unsigned* __restrict__ colw1,
        const int* __restrict__ off2, const unsigned* __restrict__ colw2,
        float* __restrict__ out) {
    int seg  = (int)((blockIdx.x * blockDim.x + threadIdx.x) >> 6);
    int lane = threadIdx.x & 63;
    if (seg >= 8 * N_NODES) return;        // 4 quarters x 2 graphs x N rows
    int q   = seg / (2 * N_NODES);         // quarter-major: phases L2-resident
    int r   = seg - q * (2 * N_NODES);
    int g   = (r >= N_NODES) ? 1 : 0;
    int row = g ? r - N_NODES : r;
    int sub = lane >> 3;                   // edge slot 0..7
    int k   = lane & 7;                    // uint2 slot (4 cols)
    const int*      off  = g ? off2  : off1;
    const unsigned* colw = g ? colw2 : colw1;
    const uint2*    xq   = xbq + (size_t)q * N_NODES * 8;
    int s = row ? off[row - 1] : 0;
    int e = off[row];

    float a0 = 0.f, a1 = 0.f, a2 = 0.f, a3 = 0.f;
    int j = s + sub;
    for (; j + 8 < e; j += 16) {           // 16 edges per wave-iteration
        unsigned c0 = colw[j];
        unsigned c1 = colw[j + 8];
        uint2 p0 = xq[(size_t)(c0 & 0xffffu) * 8 + k];
        uint2 p1 = xq[(size_t)(c1 & 0xffffu) * 8 + k];
        float w0 = __int_as_float((int)(c0 & 0xffff0000u));
        float w1 = __int_as_float((int)(c1 & 0xffff0000u));
        a0 += w0 * __int_as_float((int)(p0.x << 16));
        a1 += w0 * __int_as_float((int)(p0.x & 0xffff0000u));
        a2 += w0 * __int_as_float((int)(p0.y << 16));
        a3 += w0 * __int_as_float((int)(p0.y & 0xffff0000u));
        a0 += w1 * __int_as_float((int)(p1.x << 16));
        a1 += w1 * __int_as_float((int)(p1.x & 0xffff0000u));
        a2 += w1 * __int_as_float((int)(p1.y << 16));
        a3 += w1 * __int_as_float((int)(p1.y & 0xffff0000u));
    }
    for (; j < e; j += 8) {
        unsigned c = colw[j];
        uint2 p = xq[(size_t)(c & 0xffffu) * 8 + k];
        float w = __int_as_float((int)(c & 0xffff0000u));
        a0 += w * __int_as_float((int)(p.x << 16));
        a1 += w * __int_as_float((int)(p.x & 0xffff0000u));
        a2 += w * __int_as_float((int)(p.y << 16));
        a3 += w * __int_as_float((int)(p.y & 0xffff0000u));
    }
    // reduce across the 8 edge slots
    #pragma unroll
    for (int d = 8; d < 64; d <<= 1) {
        a0 += __shfl_xor(a0, d, 64);
        a1 += __shfl_xor(a1, d, 64);
        a2 += __shfl_xor(a2, d, 64);
        a3 += __shfl_xor(a3, d, 64);
    }
    if (sub == 0) {
        vf4 rr; rr.x = a0; rr.y = a1; rr.z = a2; rr.w = a3;
        float* o = out + (size_t)row * OUT_STRIDE + g * D + q * 32 + k * 4;
        __builtin_nontemporal_store(rr, (vf4*)o);
    }
}

// ---------------- atomic scatter (fallback if ws too small) ----------------

__global__ void spmm_scatter(const float* __restrict__ x,
                             const int* __restrict__ ei,
                             const float* __restrict__ w,
                             float* __restrict__ out,
                             int E, int col_off) {
    long long gid = (long long)blockIdx.x * blockDim.x + threadIdx.x;
    int e    = (int)(gid >> 5);
    int lane = (int)(gid & 31);
    if (e >= E) return;
    int row  = ei[e];
    int col  = ei[E + e];
    float wv = w[e];
    const float4* xv = (const float4*)(x + (size_t)col * D);
    float4 v = xv[lane];
    float* o = out + (size_t)row * OUT_STRIDE + col_off + lane * 4;
    atomicAdd(o + 0, wv * v.x);
    atomicAdd(o + 1, wv * v.y);
    atomicAdd(o + 2, wv * v.z);
    atomicAdd(o + 3, wv * v.w);
}

extern "C" void kernel_launch(void* const* d_in, const int* in_sizes, int n_in,
                              void* d_out, int out_size, void* d_ws, size_t ws_size,
                              hipStream_t stream) {
    const float* x   = (const float*)d_in[0];
    const int*   ei1 = (const int*)d_in[1];
    const float* w1  = (const float*)d_in[2];
    const int*   ei2 = (const int*)d_in[3];
    const float* w2  = (const float*)d_in[4];
    float* out = (float*)d_out;

    const int E1 = in_sizes[1] / 2;   // 800000
    const int E2 = in_sizes[3] / 2;   // 1600000
    const int block = 256;

    // Workspace: bcnt | bsBase | bsFill | off1 | off2 | inter | colw | xbq
    size_t buck_b = align256((size_t)2 * NBUCK * sizeof(int));
    size_t off_b  = align256((size_t)N_NODES * sizeof(int));
    size_t o_bcnt = 0;
    size_t o_base = o_bcnt + buck_b;
    size_t o_fill = o_base + buck_b;
    size_t o_off1 = o_fill + buck_b;
    size_t o_off2 = o_off1 + off_b;
    size_t o_int  = o_off2 + off_b;
    size_t o_colw = o_int + align256((size_t)(E1 + E2) * sizeof(uint2));
    size_t o_xb   = o_colw + align256((size_t)(E1 + E2) * sizeof(unsigned));
    size_t needed = o_xb + align256((size_t)N_NODES * 64 * sizeof(unsigned));

    if (ws_size < needed) {
        // Fallback: atomic scatter (round-0).
        (void)hipMemsetAsync(d_out, 0, (size_t)out_size * sizeof(float), stream);
        long long th1 = (long long)E1 * 32;
        spmm_scatter<<<(int)((th1 + block - 1) / block), block, 0, stream>>>(
            x, ei1, w1, out, E1, 0);
        long long th2 = (long long)E2 * 32;
        spmm_scatter<<<(int)((th2 + block - 1) / block), block, 0, stream>>>(
            x, ei2, w2, out, E2, D);
        return;
    }

    char* ws = (char*)d_ws;
    int*      bcnt   = (int*)(ws + o_bcnt);
    int*      bsBase = (int*)(ws + o_base);
    int*      bsFill = (int*)(ws + o_fill);
    int*      off1   = (int*)(ws + o_off1);
    int*      off2   = (int*)(ws + o_off2);
    uint2*    inter  = (uint2*)(ws + o_int);
    unsigned* colw   = (unsigned*)(ws + o_colw);
    uint2*    xbq    = (uint2*)(ws + o_xb);

    // 1. zero bucket counters
    (void)hipMemsetAsync(bcnt, 0, (size_t)2 * NBUCK * sizeof(int), stream);

    // 2. fused prep: coarse hist (blocks 0..511) + x pack (rest)
    {
        int n4 = N_NODES * 32;
        int cvt_blocks = (n4 + block - 1) / block;
        prep_kernel<<<HIST_BLOCKS + cvt_blocks, block, 0, stream>>>(
            ei1, E1, ei2, E2, bcnt, x, xbq, n4);
    }

    // 3. bucket bases (1 WG)
    bucket_scan<<<1, block, 0, stream>>>(bcnt, bsBase, bsFill);

    // 4. binned scatter into bucket-grouped intermediate
    {
        int nch1 = (E1 + CHUNK - 1) / CHUNK;
        int nch2 = (E2 + CHUNK - 1) / CHUNK;
        bin_scatter<<<nch1 + nch2, block, 0, stream>>>(
            ei1, w1, E1, nch1, ei2, w2, E2, bsFill, inter);
    }

    // 5. per-bucket LDS-staged counting sort -> final colw + off
    {
        dim3 g(NBUCK, 2);
        bucket_sort<<<g, block, 0, stream>>>(bsBase, bsFill, inter, colw,
                                             off1, off2, E1);
    }

    // 6. gather SpMM: wave per (quarter, graph, row), quarter-major
    {
        long long threads = (long long)8 * N_NODES * 64;
        int grid = (int)((threads + block - 1) / block);
        spmm_bf16<<<grid, block, 0, stream>>>(xbq, off1, colw,
                                              off2, colw + E1, out);
    }
}